// Round 2
// baseline (126.683 us; speedup 1.0000x reference)
//
#include <hip/hip_runtime.h>

// SSIM loss, fully fused, fp32. B=128, H=W=256, 11x11 separable Gaussian.
// Geometry: 4096 independent waves; each wave owns a 32-row x 64-col tile.
// 1024 blocks x 256 threads (4 waves/block) = 4 blocks/CU, 4 waves/SIMD.
// No barriers in the hot loop — waves are fully decoupled.

#define IMG_W 256
#define IMG_H 256
#define N_PIX (128.0f * 256.0f * 256.0f)

__global__ void ssim_init(float* out) { out[0] = 1.0f; }

__global__ __launch_bounds__(256) void ssim_main(
    const float* __restrict__ img1, const float* __restrict__ img2,
    float* __restrict__ out) {
  // 1D Gaussian, sigma=1.5, 11 taps, normalized (matches reference np window)
  const float WK[11] = {0.00102838f, 0.00759873f, 0.03600077f, 0.10936070f,
                        0.21300543f, 0.26601173f, 0.21300543f, 0.10936070f,
                        0.03600077f, 0.00759873f, 0.00102838f};

  __shared__ float2 stage[4][2][80];  // [wave][dbuf][cols: seg-8 .. seg+71]
  __shared__ float wsum[4];

  const int tid = threadIdx.x;
  const int lane = tid & 63;
  const int wid = tid >> 6;
  const int gw = blockIdx.x * 4 + wid;     // global wave id, 0..4095
  const int img = gw >> 5;                 // 32 waves per image
  const int rem = gw & 31;
  const int rs = (rem >> 2) << 5;          // strip start row (0,32,..,224)
  const int cs = (rem & 3) << 6;           // col-segment start (0,64,128,192)
  const long long ibase = (long long)img * (IMG_W * IMG_H);
  const int ce0 = cs - 8 + lane;           // col of LDS entry `lane`
  const int ce1 = cs + 56 + lane;          // col of LDS entry `64+lane` (lane<16)
  const int r0 = rs - 5;                   // first staged row

  // register ring buffer: 11 rows x 5 channels of horizontal conv results
  float rx[11], ry[11], rxx[11], ryy[11], rxy[11];
  float acc = 0.f;

  // ---- prologue: stage row r0 into buf[0]; load row r0+1 into regs ----
  float x0, y0, x1, y1;
  {
    float a0 = 0.f, b0 = 0.f, a1 = 0.f, b1 = 0.f;
    int row = r0;
    if (row >= 0) {
      long long rb = ibase + (long long)row * IMG_W;
      if (ce0 >= 0 && ce0 < IMG_W) { a0 = img1[rb + ce0]; b0 = img2[rb + ce0]; }
      if (lane < 16 && ce1 < IMG_W) { a1 = img1[rb + ce1]; b1 = img2[rb + ce1]; }
    }
    stage[wid][0][lane] = make_float2(a0, b0);
    if (lane < 16) stage[wid][0][64 + lane] = make_float2(a1, b1);
    row = r0 + 1;
    x0 = 0.f; y0 = 0.f; x1 = 0.f; y1 = 0.f;
    if (row >= 0) {
      long long rb = ibase + (long long)row * IMG_W;
      if (ce0 >= 0 && ce0 < IMG_W) { x0 = img1[rb + ce0]; y0 = img2[rb + ce0]; }
      if (lane < 16 && ce1 < IMG_W) { x1 = img1[rb + ce1]; y1 = img2[rb + ce1]; }
    }
  }

  // ---- main loop: 42 staged rows, unrolled by 11 for static ring indices ----
  for (int base_li = 0; base_li < 44; base_li += 11) {
#pragma unroll
    for (int u = 0; u < 11; ++u) {
      const int li = base_li + u;  // local row index 0..41
      if (li < 42) {
        const int r = r0 + li;
        // (1) issue global loads for row r+2 (two rows ahead)
        float nx0 = 0.f, ny0 = 0.f, nx1 = 0.f, ny1 = 0.f;
        if (li + 2 < 42) {
          const int row = r + 2;
          if (row >= 0 && row < IMG_H) {
            long long rb = ibase + (long long)row * IMG_W;
            if (ce0 >= 0 && ce0 < IMG_W) { nx0 = img1[rb + ce0]; ny0 = img2[rb + ce0]; }
            if (lane < 16 && ce1 < IMG_W) { nx1 = img1[rb + ce1]; ny1 = img2[rb + ce1]; }
          }
        }
        // (2) stage row r+1 (in regs) into the other buffer
        if (li + 1 < 42) {
          float2* wb = &stage[wid][(li + 1) & 1][0];
          wb[lane] = make_float2(x0, y0);
          if (lane < 16) wb[64 + lane] = make_float2(x1, y1);
        }
        // (3) horizontal 11-tap conv of {x,y,x2,y2,xy} from buf[li&1]
        {
          const float2* rbuf = &stage[wid][li & 1][0];
          float sx = 0.f, sy = 0.f, sxx = 0.f, syy = 0.f, sxy = 0.f;
#pragma unroll
          for (int k = 0; k < 11; ++k) {
            const float2 v = rbuf[lane + 3 + k];
            const float wk = WK[k];
            const float tx = wk * v.x;
            const float ty = wk * v.y;
            sx += tx;
            sy += ty;
            sxx = fmaf(tx, v.x, sxx);
            syy = fmaf(ty, v.y, syy);
            sxy = fmaf(tx, v.y, sxy);
          }
          rx[u] = sx; ry[u] = sy; rxx[u] = sxx; ryy[u] = syy; rxy[u] = sxy;
        }
        // (4) vertical 11-tap conv + SSIM for output row r-5
        if (li >= 10) {
          float m1 = 0.f, m2 = 0.f, e11 = 0.f, e22 = 0.f, e12 = 0.f;
#pragma unroll
          for (int j = 0; j < 11; ++j) {
            const int s = (u + 1 + j) % 11;  // compile-time ring slot
            const float wj = WK[j];
            m1 = fmaf(wj, rx[s], m1);
            m2 = fmaf(wj, ry[s], m2);
            e11 = fmaf(wj, rxx[s], e11);
            e22 = fmaf(wj, ryy[s], e22);
            e12 = fmaf(wj, rxy[s], e12);
          }
          const float C1 = 1e-4f, C2 = 9e-4f;
          const float mu11 = m1 * m1, mu22 = m2 * m2, mu12 = m1 * m2;
          const float s11 = e11 - mu11, s22 = e22 - mu22, s12 = e12 - mu12;
          const float num = (2.f * mu12 + C1) * (2.f * s12 + C2);
          const float den = (mu11 + mu22 + C1) * (s11 + s22 + C2);
          float rcp = __builtin_amdgcn_rcpf(den);
          rcp = rcp * fmaf(-den, rcp, 2.0f);  // one Newton step
          acc = fmaf(num, rcp, acc);
        }
        x0 = nx0; y0 = ny0; x1 = nx1; y1 = ny1;
      }
    }
  }

  // ---- reduction: wave shuffle -> block LDS -> one atomic per block ----
  acc += __shfl_down(acc, 32);
  acc += __shfl_down(acc, 16);
  acc += __shfl_down(acc, 8);
  acc += __shfl_down(acc, 4);
  acc += __shfl_down(acc, 2);
  acc += __shfl_down(acc, 1);
  if (lane == 0) wsum[wid] = acc;
  __syncthreads();
  if (tid == 0) {
    const float s = wsum[0] + wsum[1] + wsum[2] + wsum[3];
    atomicAdd(out, s * (-1.0f / N_PIX));
  }
}

extern "C" void kernel_launch(void* const* d_in, const int* in_sizes, int n_in,
                              void* d_out, int out_size, void* d_ws,
                              size_t ws_size, hipStream_t stream) {
  const float* img1 = (const float*)d_in[0];
  const float* img2 = (const float*)d_in[1];
  float* out = (float*)d_out;
  ssim_init<<<1, 1, 0, stream>>>(out);
  ssim_main<<<1024, 256, 0, stream>>>(img1, img2, out);
}

// Round 3
// 120.524 us; speedup vs baseline: 1.0511x; 1.0511x over previous
//
#include <hip/hip_runtime.h>

// SSIM loss, fully fused, fp32. B=128, H=W=256, 11x11 separable Gaussian.
// Geometry: 4096 independent waves; each wave owns a 32-row x 64-col tile.
// 1024 blocks x 256 threads (4 waves/block) = 4 blocks/CU, 4 waves/SIMD.
// All row/address math forced scalar (readfirstlane); bounds via clamp+mask.

#define IMG_W 256
#define IMG_H 256
#define N_PIX (128.0f * 256.0f * 256.0f)

__global__ void ssim_init(float* out) { out[0] = 1.0f; }

__global__ __launch_bounds__(256) void ssim_main(
    const float* __restrict__ img1, const float* __restrict__ img2,
    float* __restrict__ out) {
  // 1D Gaussian, sigma=1.5, 11 taps, normalized (matches reference np window)
  const float WK[11] = {0.00102838f, 0.00759873f, 0.03600077f, 0.10936070f,
                        0.21300543f, 0.26601173f, 0.21300543f, 0.10936070f,
                        0.03600077f, 0.00759873f, 0.00102838f};

  __shared__ float2 stage[4][2][128];  // [wave][dbuf][128 cols] (reads use 0..79)
  __shared__ float wsum[4];

  const int tid = threadIdx.x;
  const int lane = tid & 63;
  const int wid = tid >> 6;
  // wave coordinates -- force into SGPRs so all row/address math is SALU
  const int gw = __builtin_amdgcn_readfirstlane(blockIdx.x * 4 + wid);
  const int img = gw >> 5;                 // 32 waves per image
  const int rem = gw & 31;
  const int rs = (rem >> 2) << 5;          // strip start row (0,32,..,224)
  const int cs = (rem & 3) << 6;           // col-segment start (0,64,128,192)
  const int r0 = rs - 5;                   // first staged row
  const char* q1 = (const char*)(img1 + (size_t)img * (IMG_W * IMG_H));
  const char* q2 = (const char*)(img2 + (size_t)img * (IMG_W * IMG_H));

  // per-lane column byte-offsets (clamped) + float masks, row-invariant
  const int c0 = cs - 8 + lane;            // in [-8, 247] -> only underflow
  const int c1 = c0 + 64;                  // in [56, 311] -> only overflow
  const float cm0 = (c0 >= 0) ? 1.0f : 0.0f;
  const float cm1 = (c1 < IMG_W) ? 1.0f : 0.0f;
  const int co0 = (c0 < 0 ? 0 : c0) * 4;
  const int co1 = (c1 > IMG_W - 1 ? IMG_W - 1 : c1) * 4;

// row ri (scalar): clamped byte offset of row start
#define ROWOFF(ri) (((ri) < 0 ? 0 : ((ri) > IMG_H - 1 ? IMG_H - 1 : (ri))) << 10)
// load row ri's 4 values for this lane, col-masked
#define LOADROW(ri, X0, Y0, X1, Y1)                  \
  {                                                  \
    const int ro_ = ROWOFF(ri);                      \
    const int o0_ = ro_ + co0, o1_ = ro_ + co1;      \
    X0 = *(const float*)(q1 + o0_) * cm0;            \
    Y0 = *(const float*)(q2 + o0_) * cm0;            \
    X1 = *(const float*)(q1 + o1_) * cm1;            \
    Y1 = *(const float*)(q2 + o1_) * cm1;            \
  }

  // register ring buffer: 11 rows x 5 channels of horizontal conv results
  float rx[11], ry[11], rxx[11], ryy[11], rxy[11];
  float acc = 0.f;

  // ---- prologue: stage row r0 into buf[0]; load row r0+1 into regs ----
  float x0, y0, x1, y1;
  {
    float a0, b0, a1, b1;
    LOADROW(r0, a0, b0, a1, b1);
    stage[wid][0][lane] = make_float2(a0, b0);
    stage[wid][0][64 + lane] = make_float2(a1, b1);
    LOADROW(r0 + 1, x0, y0, x1, y1);
  }

  // ---- main loop: 42 staged rows, unrolled by 11 for static ring indices ----
  for (int bl = 0; bl < 44; bl += 11) {
#pragma unroll
    for (int u = 0; u < 11; ++u) {
      const int li = bl + u;  // local row index 0..43 (guarded)
      if (li < 42) {
        const int ri = r0 + li;
        // (1) issue global loads for row ri+2 (two rows ahead)
        float nx0 = 0.f, ny0 = 0.f, nx1 = 0.f, ny1 = 0.f;
        if (li + 2 < 42) LOADROW(ri + 2, nx0, ny0, nx1, ny1);
        // (2) stage row ri+1 (in regs) into the other buffer
        if (li + 1 < 42) {
          float2* wb = &stage[wid][(li + 1) & 1][0];
          wb[lane] = make_float2(x0, y0);
          wb[64 + lane] = make_float2(x1, y1);
        }
        // (3) horizontal 11-tap conv of {x,y,x2,y2,xy} from buf[li&1]
        {
          const float2* rbuf = &stage[wid][li & 1][0];
          float sx = 0.f, sy = 0.f, sxx = 0.f, syy = 0.f, sxy = 0.f;
#pragma unroll
          for (int k = 0; k < 11; ++k) {
            const float2 v = rbuf[lane + 3 + k];
            const float wk = WK[k];
            const float tx = wk * v.x;
            const float ty = wk * v.y;
            sx += tx;
            sy += ty;
            sxx = fmaf(tx, v.x, sxx);
            syy = fmaf(ty, v.y, syy);
            sxy = fmaf(tx, v.y, sxy);
          }
          // row-validity: wave-uniform scalar branch, no per-lane predication
          if (ri >= 0 && ri < IMG_H) {
            rx[u] = sx; ry[u] = sy; rxx[u] = sxx; ryy[u] = syy; rxy[u] = sxy;
          } else {
            rx[u] = 0.f; ry[u] = 0.f; rxx[u] = 0.f; ryy[u] = 0.f; rxy[u] = 0.f;
          }
        }
        // (4) vertical 11-tap conv + SSIM for output row ri-5
        if (li >= 10) {
          float m1 = 0.f, m2 = 0.f, e11 = 0.f, e22 = 0.f, e12 = 0.f;
#pragma unroll
          for (int j = 0; j < 11; ++j) {
            const int s = (u + 1 + j) % 11;  // compile-time ring slot
            const float wj = WK[j];
            m1 = fmaf(wj, rx[s], m1);
            m2 = fmaf(wj, ry[s], m2);
            e11 = fmaf(wj, rxx[s], e11);
            e22 = fmaf(wj, ryy[s], e22);
            e12 = fmaf(wj, rxy[s], e12);
          }
          const float C1 = 1e-4f, C2 = 9e-4f;
          const float mu11 = m1 * m1, mu22 = m2 * m2, mu12 = m1 * m2;
          const float s11 = e11 - mu11, s22 = e22 - mu22, s12 = e12 - mu12;
          const float num = (2.f * mu12 + C1) * (2.f * s12 + C2);
          const float den = (mu11 + mu22 + C1) * (s11 + s22 + C2);
          float rcp = __builtin_amdgcn_rcpf(den);
          rcp = rcp * fmaf(-den, rcp, 2.0f);  // one Newton step
          acc = fmaf(num, rcp, acc);
        }
        x0 = nx0; y0 = ny0; x1 = nx1; y1 = ny1;
      }
    }
  }

  // ---- reduction: wave shuffle -> block LDS -> one atomic per block ----
  acc += __shfl_down(acc, 32);
  acc += __shfl_down(acc, 16);
  acc += __shfl_down(acc, 8);
  acc += __shfl_down(acc, 4);
  acc += __shfl_down(acc, 2);
  acc += __shfl_down(acc, 1);
  if (lane == 0) wsum[wid] = acc;
  __syncthreads();
  if (tid == 0) {
    const float s = wsum[0] + wsum[1] + wsum[2] + wsum[3];
    atomicAdd(out, s * (-1.0f / N_PIX));
  }
}

extern "C" void kernel_launch(void* const* d_in, const int* in_sizes, int n_in,
                              void* d_out, int out_size, void* d_ws,
                              size_t ws_size, hipStream_t stream) {
  const float* img1 = (const float*)d_in[0];
  const float* img2 = (const float*)d_in[1];
  float* out = (float*)d_out;
  ssim_init<<<1, 1, 0, stream>>>(out);
  ssim_main<<<1024, 256, 0, stream>>>(img1, img2, out);
}